// Round 5
// baseline (322.140 us; speedup 1.0000x reference)
//
#include <hip/hip_runtime.h>

#define POOL 14
#define IMG_H 128
#define IMG_W 128
#define IMG_C 1024
#define NROI 256

typedef __attribute__((ext_vector_type(4))) float float4v;

__global__ __launch_bounds__(256) void roi_resize_kernel(
    const float* __restrict__ img,    // fp32, [128][128][1024]
    const float* __restrict__ rois,   // fp32, [256][4]
    float* __restrict__ out)          // fp32, [256][14][14][1024]
{
    const int p = blockIdx.x;                       // pixel index in [0, 256*14*14)

    const int r   = p / (POOL * POOL);
    const int rem = p - r * (POOL * POOL);
    const int i   = rem / POOL;                     // pooled y
    const int j   = rem - i * POOL;                 // pooled x

    // ROI params (uniform across the block)
    const int x1 = (int)rois[r * 4 + 0];
    const int y1 = (int)rois[r * 4 + 1];
    const int x2 = (int)rois[r * 4 + 2];
    const int y2 = (int)rois[r * 4 + 3];
    const int h = y2 - y1;
    const int w = x2 - x1;

    // Replicate reference fp32 math exactly: src = i * (h / 14.0f)
    const float src_y = (float)i * ((float)h / (float)POOL);
    const float src_x = (float)j * ((float)w / (float)POOL);
    const int y0 = (int)floorf(src_y);
    const int x0 = (int)floorf(src_x);
    const float fy = src_y - (float)y0;
    const float fx = src_x - (float)x0;
    const int y1i = min(y0 + 1, h - 1);
    const int x1i = min(x0 + 1, w - 1);
    const int ay0 = min(max(y1 + y0,  0), IMG_H - 1);
    const int ay1 = min(max(y1 + y1i, 0), IMG_H - 1);
    const int ax0 = min(max(x1 + x0,  0), IMG_W - 1);
    const int ax1 = min(max(x1 + x1i, 0), IMG_W - 1);

    const float* p00 = img + (size_t)(ay0 * IMG_W + ax0) * IMG_C;
    const float* p01 = img + (size_t)(ay0 * IMG_W + ax1) * IMG_C;
    const float* p10 = img + (size_t)(ay1 * IMG_W + ax0) * IMG_C;
    const float* p11 = img + (size_t)(ay1 * IMG_W + ax1) * IMG_C;
    float* po = out + (size_t)p * IMG_C;

    const int c = threadIdx.x * 4;                  // 256 threads * 4 ch = 1024 ch

    const float4v v00 = *(const float4v*)(p00 + c);
    const float4v v01 = *(const float4v*)(p01 + c);
    const float4v v10 = *(const float4v*)(p10 + c);
    const float4v v11 = *(const float4v*)(p11 + c);

    float4v o;
    #pragma unroll
    for (int k = 0; k < 4; ++k) {
        const float top = v00[k] + (v01[k] - v00[k]) * fx;
        const float bot = v10[k] + (v11[k] - v10[k]) * fx;
        o[k] = top + (bot - top) * fy;
    }
    *(float4v*)(po + c) = o;
}

extern "C" void kernel_launch(void* const* d_in, const int* in_sizes, int n_in,
                              void* d_out, int out_size, void* d_ws, size_t ws_size,
                              hipStream_t stream) {
    const float* img  = (const float*)d_in[0];
    const float* rois = (const float*)d_in[1];
    float* out = (float*)d_out;

    const int pixels = NROI * POOL * POOL;          // 50176 blocks, 1 pixel each
    roi_resize_kernel<<<pixels, 256, 0, stream>>>(img, rois, out);
}

// Round 6
// 302.574 us; speedup vs baseline: 1.0647x; 1.0647x over previous
//
#include <hip/hip_runtime.h>

#define POOL 14
#define IMG_H 128
#define IMG_W 128
#define IMG_C 1024
#define NROI 256

typedef __attribute__((ext_vector_type(4))) float float4v;

__global__ __launch_bounds__(256) void roi_resize_kernel(
    const float* __restrict__ img,    // fp32, [128][128][1024]
    const float* __restrict__ rois,   // fp32, [256][4]
    float* __restrict__ out)          // fp32, [256][14][14][1024]
{
    // XCD-aware swizzle: dispatch id d lands on XCD d%8 (measured mapping).
    // Bind all 196 pixel-blocks of one ROI to one XCD so their shared
    // gathered rows are fetched by ONE L2 instead of up to 8.
    // 50176 blocks = 8 xcd * 32 roi_within * 196 pix  (bijective decode)
    const int d    = blockIdx.x;
    const int xcd  = d & 7;
    const int slot = d >> 3;                        // [0, 6272)
    const int rwi  = slot / (POOL * POOL);          // [0, 32) roi-within-xcd
    const int pix  = slot - rwi * (POOL * POOL);    // [0, 196)
    const int r    = rwi * 8 + xcd;                 // ROI index
    const int i    = pix / POOL;                    // pooled y
    const int j    = pix - i * POOL;                // pooled x

    // ROI params (uniform across the block)
    const int x1 = (int)rois[r * 4 + 0];
    const int y1 = (int)rois[r * 4 + 1];
    const int x2 = (int)rois[r * 4 + 2];
    const int y2 = (int)rois[r * 4 + 3];
    const int h = y2 - y1;
    const int w = x2 - x1;

    // Replicate reference fp32 math exactly: src = i * (h / 14.0f)
    const float src_y = (float)i * ((float)h / (float)POOL);
    const float src_x = (float)j * ((float)w / (float)POOL);
    const int y0 = (int)floorf(src_y);
    const int x0 = (int)floorf(src_x);
    const float fy = src_y - (float)y0;
    const float fx = src_x - (float)x0;
    const int y1i = min(y0 + 1, h - 1);
    const int x1i = min(x0 + 1, w - 1);
    const int ay0 = min(max(y1 + y0,  0), IMG_H - 1);
    const int ay1 = min(max(y1 + y1i, 0), IMG_H - 1);
    const int ax0 = min(max(x1 + x0,  0), IMG_W - 1);
    const int ax1 = min(max(x1 + x1i, 0), IMG_W - 1);

    const float* p00 = img + (size_t)(ay0 * IMG_W + ax0) * IMG_C;
    const float* p01 = img + (size_t)(ay0 * IMG_W + ax1) * IMG_C;
    const float* p10 = img + (size_t)(ay1 * IMG_W + ax0) * IMG_C;
    const float* p11 = img + (size_t)(ay1 * IMG_W + ax1) * IMG_C;
    float* po = out + ((size_t)r * (POOL * POOL) + pix) * IMG_C;

    const int c = threadIdx.x * 4;                  // 256 threads * 4 ch = 1024 ch

    const float4v v00 = *(const float4v*)(p00 + c);
    const float4v v01 = *(const float4v*)(p01 + c);
    const float4v v10 = *(const float4v*)(p10 + c);
    const float4v v11 = *(const float4v*)(p11 + c);

    float4v o;
    #pragma unroll
    for (int k = 0; k < 4; ++k) {
        const float top = v00[k] + (v01[k] - v00[k]) * fx;
        const float bot = v10[k] + (v11[k] - v10[k]) * fx;
        o[k] = top + (bot - top) * fy;
    }
    *(float4v*)(po + c) = o;
}

extern "C" void kernel_launch(void* const* d_in, const int* in_sizes, int n_in,
                              void* d_out, int out_size, void* d_ws, size_t ws_size,
                              hipStream_t stream) {
    const float* img  = (const float*)d_in[0];
    const float* rois = (const float*)d_in[1];
    float* out = (float*)d_out;

    const int pixels = NROI * POOL * POOL;          // 50176 blocks, 1 pixel each
    roi_resize_kernel<<<pixels, 256, 0, stream>>>(img, rois, out);
}

// Round 7
// 298.503 us; speedup vs baseline: 1.0792x; 1.0136x over previous
//
#include <hip/hip_runtime.h>

#define POOL 14
#define IMG_H 128
#define IMG_W 128
#define IMG_C 1024
#define NROI 256

typedef __attribute__((ext_vector_type(4))) float float4v;

__global__ __launch_bounds__(256) void roi_resize_kernel(
    const float* __restrict__ img,    // fp32, [128][128][1024]
    const float* __restrict__ rois,   // fp32, [256][4]
    float* __restrict__ out)          // fp32, [256][14][14][1024]
{
    // One block = one (ROI, pool-row): 14 output pixels, serial over j.
    //  - ROI decode amortized 14x; corners reused through L1 across j
    //  - XCD-aware swizzle: 3584 blocks = 8 xcd * 32 roi_within * 14 rows
    const int d    = blockIdx.x;
    const int xcd  = d & 7;
    const int slot = d >> 3;                        // [0, 448)
    const int rwi  = slot / POOL;                   // [0, 32) roi-within-xcd
    const int i    = slot - rwi * POOL;             // [0, 14) pool row
    const int r    = rwi * 8 + xcd;                 // ROI index

    // ROI params (uniform across the block)
    const int x1 = (int)rois[r * 4 + 0];
    const int y1 = (int)rois[r * 4 + 1];
    const int x2 = (int)rois[r * 4 + 2];
    const int y2 = (int)rois[r * 4 + 3];
    const int h = y2 - y1;
    const int w = x2 - x1;

    // Row math (uniform): src = i * (h / 14.0f), exactly as the reference
    const float src_y = (float)i * ((float)h / (float)POOL);
    const int y0 = (int)floorf(src_y);
    const float fy = src_y - (float)y0;
    const int y1i = min(y0 + 1, h - 1);
    const int ay0 = min(max(y1 + y0,  0), IMG_H - 1);
    const int ay1 = min(max(y1 + y1i, 0), IMG_H - 1);

    const float* row0 = img + (size_t)(ay0 * IMG_W) * IMG_C;
    const float* row1 = img + (size_t)(ay1 * IMG_W) * IMG_C;

    const int c = threadIdx.x * 4;                  // 256 threads * 4 ch = 1024 ch
    float* po = out + ((size_t)r * (POOL * POOL) + (size_t)i * POOL) * IMG_C + c;

    const float winv = (float)w / (float)POOL;

    #pragma unroll 2
    for (int j = 0; j < POOL; ++j) {
        const float src_x = (float)j * winv;
        const int x0 = (int)floorf(src_x);
        const float fx = src_x - (float)x0;
        const int x1i = min(x0 + 1, w - 1);
        const int ax0 = min(max(x1 + x0,  0), IMG_W - 1);
        const int ax1 = min(max(x1 + x1i, 0), IMG_W - 1);

        const float4v v00 = *(const float4v*)(row0 + (size_t)ax0 * IMG_C + c);
        const float4v v01 = *(const float4v*)(row0 + (size_t)ax1 * IMG_C + c);
        const float4v v10 = *(const float4v*)(row1 + (size_t)ax0 * IMG_C + c);
        const float4v v11 = *(const float4v*)(row1 + (size_t)ax1 * IMG_C + c);

        float4v o;
        #pragma unroll
        for (int k = 0; k < 4; ++k) {
            const float top = v00[k] + (v01[k] - v00[k]) * fx;
            const float bot = v10[k] + (v11[k] - v10[k]) * fx;
            o[k] = top + (bot - top) * fy;
        }
        // Streaming output, never re-read: keep it out of L2 so the
        // gather working set stays resident.
        __builtin_nontemporal_store(o, (float4v*)(po + (size_t)j * IMG_C));
    }
}

extern "C" void kernel_launch(void* const* d_in, const int* in_sizes, int n_in,
                              void* d_out, int out_size, void* d_ws, size_t ws_size,
                              hipStream_t stream) {
    const float* img  = (const float*)d_in[0];
    const float* rois = (const float*)d_in[1];
    float* out = (float*)d_out;

    const int blocks = NROI * POOL;                 // 3584: one (roi, pool-row) each
    roi_resize_kernel<<<blocks, 256, 0, stream>>>(img, rois, out);
}